// Round 2
// baseline (101.665 us; speedup 1.0000x reference)
//
#include <hip/hip_runtime.h>

// SIMDIS: mean cosine similarity -> bottom-100 argsort -> gather.
// mean_sim_i = (x_i . s) / (n_i * N), s = sum_j x_j / n_j  -> O(N*D), 2 passes.
// s accumulated via deterministic i64 fixed-point atomics (scale 2^44):
// integer adds commute, so validate == replay bit-exactly; quantization
// error ~2^-38 vs rank-100 score gaps ~2e-6.

#define N 8192
#define D 512
#define K 100
#define ROWS_PER_BLK 16   // pass1: 512 blocks x 16 rows

typedef unsigned long long u64;
typedef unsigned int u32;

#define SCALE 17592186044416.0          // 2^44
#define INV_SCALE (1.0 / 17592186044416.0)

__device__ __forceinline__ u32 f32_sortable(float f) {
    u32 u = __float_as_uint(f);
    return (u & 0x80000000u) ? ~u : (u | 0x80000000u);
}

// Pass 1 (fused): per-block row norms (HBM read) + fixed-point column-sum
// accumulation (L1/L2 re-read of the same 32 KB). 512 blocks x 256 threads.
__global__ __launch_bounds__(256) void pass1_k(const float* __restrict__ x,
                                               double* __restrict__ inv_n,
                                               u64* __restrict__ s_fix) {
    __shared__ double inv_loc[ROWS_PER_BLK];
    int t = threadIdx.x;
    int lane = t & 63, wave = t >> 6;
    int row0 = blockIdx.x * ROWS_PER_BLK;

    // Phase 1: wave per row, 4 rows per wave.
    for (int i = 0; i < ROWS_PER_BLK / 4; ++i) {
        int li = wave * (ROWS_PER_BLK / 4) + i;
        int r = row0 + li;
        const float4* xr = (const float4*)(x + (size_t)r * D);
        float4 a = xr[lane];
        float4 b = xr[lane + 64];
        double sm = (double)a.x * a.x + (double)a.y * a.y + (double)a.z * a.z + (double)a.w * a.w
                  + (double)b.x * b.x + (double)b.y * b.y + (double)b.z * b.z + (double)b.w * b.w;
        for (int off = 32; off > 0; off >>= 1) sm += __shfl_down(sm, off);
        if (lane == 0) {
            double v = 1.0 / sqrt(sm);
            inv_n[r] = v;
            inv_loc[li] = v;
        }
    }
    __syncthreads();

    // Phase 2: thread t accumulates cols t and t+256 over this block's rows.
    double a0 = 0.0, a1 = 0.0;
    for (int r = 0; r < ROWS_PER_BLK; ++r) {
        double w = inv_loc[r];                      // LDS broadcast
        const float* xr = x + (size_t)(row0 + r) * D;  // L1/L2-hot
        a0 += (double)xr[t] * w;
        a1 += (double)xr[t + 256] * w;
    }
    atomicAdd(s_fix + t,       (u64)(long long)__double2ll_rn(a0 * SCALE));
    atomicAdd(s_fix + t + 256, (u64)(long long)__double2ll_rn(a1 * SCALE));
}

// Pass 2: one wave per row: score = (x_row . s) * inv_n[row] (monotone in
// mean_sim). Pack sortable-f32(score)<<32 | row -> stable ascending argsort.
__global__ __launch_bounds__(256) void score_k(const float* __restrict__ x,
                                               const double* __restrict__ inv_n,
                                               const u64* __restrict__ s_fix,
                                               u64* __restrict__ keys) {
    int lane = threadIdx.x & 63;
    int row  = (blockIdx.x << 2) + (threadIdx.x >> 6);
    const float4* xr = (const float4*)(x + (size_t)row * D);
    float4 a = xr[lane];
    float4 b = xr[lane + 64];
    const long long* sf = (const long long*)s_fix;
    int c0 = lane * 4, c1 = (lane + 64) * 4;
    double acc = (double)a.x * ((double)sf[c0]     * INV_SCALE)
               + (double)a.y * ((double)sf[c0 + 1] * INV_SCALE)
               + (double)a.z * ((double)sf[c0 + 2] * INV_SCALE)
               + (double)a.w * ((double)sf[c0 + 3] * INV_SCALE)
               + (double)b.x * ((double)sf[c1]     * INV_SCALE)
               + (double)b.y * ((double)sf[c1 + 1] * INV_SCALE)
               + (double)b.z * ((double)sf[c1 + 2] * INV_SCALE)
               + (double)b.w * ((double)sf[c1 + 3] * INV_SCALE);
    for (int off = 32; off > 0; off >>= 1) acc += __shfl_down(acc, off);
    if (lane == 0) {
        float sc = (float)(acc * inv_n[row]);
        keys[row] = ((u64)f32_sortable(sc) << 32) | (u32)row;
    }
}

// In-LDS bitonic sort, ascending, blockDim.x == NELEM (power of 2).
template <int NELEM>
__device__ __forceinline__ void bitonic_sort(u64* lds) {
    int t = threadIdx.x;
    for (int k = 2; k <= NELEM; k <<= 1) {
        for (int j = k >> 1; j > 0; j >>= 1) {
            int ixj = t ^ j;
            if (ixj > t) {
                u64 a = lds[t], b = lds[ixj];
                bool up = ((t & k) == 0);
                if ((a > b) == up) { lds[t] = b; lds[ixj] = a; }
            }
            __syncthreads();
        }
    }
}

// Stage 1: 8 blocks x 1024 keys; keep each block's bottom 128 (sorted).
// Any global bottom-100 element has rank < 128 within its own block.
__global__ __launch_bounds__(1024) void select1_k(const u64* __restrict__ keys,
                                                  u64* __restrict__ cand) {
    __shared__ u64 lds[1024];
    int t = threadIdx.x;
    lds[t] = keys[blockIdx.x * 1024 + t];
    __syncthreads();
    bitonic_sort<1024>(lds);
    if (t < 128) cand[blockIdx.x * 128 + t] = lds[t];
}

// Stage 2 (fused with gather): sort 1024 candidates; first 100 are the
// answer in order. Write indices, then gather the 100 rows (bit-exact).
__global__ __launch_bounds__(1024) void select2_k(const u64* __restrict__ cand,
                                                  const float* __restrict__ x,
                                                  float* __restrict__ out) {
    __shared__ u64 lds[1024];
    __shared__ int sel[K];
    int t = threadIdx.x;
    lds[t] = cand[t];
    __syncthreads();
    bitonic_sort<1024>(lds);
    if (t < K) {
        int idx = (int)(u32)(lds[t] & 0xffffffffu);
        sel[t] = idx;
        out[(size_t)K * D + t] = (float)idx;   // indices exact in f32
    }
    __syncthreads();
    const float4* xv = (const float4*)x;
    float4* ov = (float4*)out;
    for (int i = t; i < K * (D / 4); i += 1024) {
        int g = i >> 7, e = i & 127;           // row-of-100, float4-elem
        ov[(size_t)g * (D / 4) + e] = xv[(size_t)sel[g] * (D / 4) + e];
    }
}

extern "C" void kernel_launch(void* const* d_in, const int* in_sizes, int n_in,
                              void* d_out, int out_size, void* d_ws, size_t ws_size,
                              hipStream_t stream) {
    const float* x = (const float*)d_in[0];
    float* out = (float*)d_out;               // [K*D gathered rows][K indices]

    char* ws = (char*)d_ws;
    double* inv_n = (double*)(ws);            // 8192 * 8 = 65536
    u64*    s_fix = (u64*)   (ws + 65536);    //  512 * 8 =  4096
    u64*    keys  = (u64*)   (ws + 69632);    // 8192 * 8 = 65536
    u64*    cand  = (u64*)   (ws + 135168);   // 1024 * 8 =  8192

    hipMemsetAsync(s_fix, 0, D * sizeof(u64), stream);
    pass1_k  <<<N / ROWS_PER_BLK, 256, 0, stream>>>(x, inv_n, s_fix);
    score_k  <<<N / 4, 256, 0, stream>>>(x, inv_n, s_fix, keys);
    select1_k<<<8, 1024, 0, stream>>>(keys, cand);
    select2_k<<<1, 1024, 0, stream>>>(cand, x, out);
}